// Round 1
// baseline (310.908 us; speedup 1.0000x reference)
//
#include <hip/hip_runtime.h>
#include <math.h>

// Problem constants
#define BT    96          // B*T = 8*12
#define NSEQ  512         // N
#define DMODEL 64         // D = K*d
#define RTOT  (BT * NSEQ) // 49152 rows

// Workspace layout (floats)
#define QOFF  0
#define KOFF  ((size_t)RTOT * DMODEL)          // 3145728
#define VOFF  ((size_t)2 * RTOT * DMODEL)
#define OOFF  ((size_t)3 * RTOT * DMODEL)      // attention output

// ---------------------------------------------------------------------------
// Kernel 1: QKV = relu([X|STE] @ W{7,8,9} + b{7,8,9})
// grid (RTOT/128, 3), block 256. Tile: 128 rows x 64 cols, thread 8x4.
// K=128 streamed in 4 chunks of 32 (kc 0..1 from X, 2..3 from STE).
// ---------------------------------------------------------------------------
__global__ __launch_bounds__(256) void qkv_kernel(
    const float* __restrict__ X, const float* __restrict__ STE,
    const float* __restrict__ W7, const float* __restrict__ b7,
    const float* __restrict__ W8, const float* __restrict__ b8,
    const float* __restrict__ W9, const float* __restrict__ b9,
    float* __restrict__ qkv)
{
    __shared__ float As[128][36];   // pad 36: rows 144B (16B-aligned for b128)
    __shared__ float Ws[32][68];    // pad 68: rows 272B (16B-aligned)

    const int tid  = threadIdx.x;
    const int tx   = tid & 15;      // col group: cols tx*4..tx*4+3
    const int ty   = tid >> 4;      // row group: rows ty*8..ty*8+7
    const int rt   = blockIdx.x;    // 128-row tile
    const int wsel = blockIdx.y;    // 0:Q 1:K 2:V

    const float* Wm = (wsel == 0) ? W7 : (wsel == 1) ? W8 : W9;
    const float* bv = (wsel == 0) ? b7 : (wsel == 1) ? b8 : b9;

    float acc[8][4];
    #pragma unroll
    for (int i = 0; i < 8; ++i)
        #pragma unroll
        for (int j = 0; j < 4; ++j) acc[i][j] = 0.f;

    const size_t rowbase = (size_t)rt * 128;

    for (int kc = 0; kc < 4; ++kc) {
        const float* src = (kc < 2) ? X : STE;
        const int koff = (kc & 1) * 32;

        __syncthreads();
        // Stage A chunk: 128 rows x 32 k  (1024 float4, 4 per thread)
        #pragma unroll
        for (int j = 0; j < 4; ++j) {
            int idx = tid + 256 * j;
            int r   = idx >> 3;
            int kq  = (idx & 7) * 4;
            float4 v = *(const float4*)(src + (rowbase + (size_t)r) * 64 + koff + kq);
            *(float4*)&As[r][kq] = v;
        }
        // Stage W chunk: 32 k x 64 cols  (512 float4, 2 per thread)
        #pragma unroll
        for (int j = 0; j < 2; ++j) {
            int idx = tid + 256 * j;
            int kk  = idx >> 4;
            int cq  = (idx & 15) * 4;
            float4 v = *(const float4*)(Wm + (size_t)(kc * 32 + kk) * 64 + cq);
            *(float4*)&Ws[kk][cq] = v;
        }
        __syncthreads();

        #pragma unroll
        for (int k0 = 0; k0 < 32; k0 += 4) {
            float4 a[8], w[4];
            #pragma unroll
            for (int i = 0; i < 8; ++i) a[i] = *(const float4*)&As[ty * 8 + i][k0];
            #pragma unroll
            for (int j = 0; j < 4; ++j) w[j] = *(const float4*)&Ws[k0 + j][tx * 4];
            #pragma unroll
            for (int i = 0; i < 8; ++i) {
                acc[i][0] += a[i].x * w[0].x + a[i].y * w[1].x + a[i].z * w[2].x + a[i].w * w[3].x;
                acc[i][1] += a[i].x * w[0].y + a[i].y * w[1].y + a[i].z * w[2].y + a[i].w * w[3].y;
                acc[i][2] += a[i].x * w[0].z + a[i].y * w[1].z + a[i].z * w[2].z + a[i].w * w[3].z;
                acc[i][3] += a[i].x * w[0].w + a[i].y * w[1].w + a[i].z * w[2].w + a[i].w * w[3].w;
            }
        }
    }

    float* obase = qkv + (size_t)wsel * ((size_t)RTOT * DMODEL) + rowbase * 64;
    const float4 bb = *(const float4*)(bv + tx * 4);
    #pragma unroll
    for (int i = 0; i < 8; ++i) {
        float4 o;
        o.x = fmaxf(acc[i][0] + bb.x, 0.f);
        o.y = fmaxf(acc[i][1] + bb.y, 0.f);
        o.z = fmaxf(acc[i][2] + bb.z, 0.f);
        o.w = fmaxf(acc[i][3] + bb.w, 0.f);
        *(float4*)(obase + (size_t)(ty * 8 + i) * 64 + tx * 4) = o;
    }
}

// ---------------------------------------------------------------------------
// Kernel 2: per (bt, head) attention. grid 768, block 256 (2 q-rows/thread).
// relu'd q,k => scores >= 0 and bounded => one-pass softmax without max:
//   out = (sum_m exp(s_m) v_m) / (sum_m exp(s_m)),  exp via exp2 with
//   log2(e)/sqrt(8) folded into q at load.
// LDS: q/k/v head slices [512][8] fp32 = 48KB (3 blocks/CU).
// ---------------------------------------------------------------------------
__global__ __launch_bounds__(256) void attn_kernel(
    const float* __restrict__ qkv, float* __restrict__ obuf)
{
    __shared__ float qs[NSEQ][8];
    __shared__ float ks[NSEQ][8];
    __shared__ float vs[NSEQ][8];

    const int tid = threadIdx.x;
    const int h   = blockIdx.x & 7;
    const int bt  = blockIdx.x >> 3;

    const float* Qp = qkv + QOFF;
    const float* Kp = qkv + KOFF;
    const float* Vp = qkv + VOFF;
    const size_t rowbase = (size_t)bt * NSEQ * 64 + (size_t)h * 8;

    #pragma unroll
    for (int j = 0; j < 4; ++j) {
        int idx  = tid + 256 * j;
        int n    = idx >> 1;
        int half = (idx & 1) * 4;
        size_t g = rowbase + (size_t)n * 64 + half;
        *(float4*)&qs[n][half] = *(const float4*)(Qp + g);
        *(float4*)&ks[n][half] = *(const float4*)(Kp + g);
        *(float4*)&vs[n][half] = *(const float4*)(Vp + g);
    }
    __syncthreads();

    const float C = 0.51012091684045906f;  // log2(e) / sqrt(8)
    const int n0 = tid * 2;
    float q0[8], q1[8];
    #pragma unroll
    for (int j = 0; j < 8; ++j) { q0[j] = qs[n0][j] * C; q1[j] = qs[n0 + 1][j] * C; }

    float acc0[8], acc1[8];
    #pragma unroll
    for (int j = 0; j < 8; ++j) { acc0[j] = 0.f; acc1[j] = 0.f; }
    float d0 = 0.f, d1 = 0.f;

    #pragma unroll 4
    for (int m = 0; m < NSEQ; ++m) {
        const float4 ka = *(const float4*)&ks[m][0];
        const float4 kb = *(const float4*)&ks[m][4];
        float s0 = q0[0] * ka.x + q0[1] * ka.y + q0[2] * ka.z + q0[3] * ka.w
                 + q0[4] * kb.x + q0[5] * kb.y + q0[6] * kb.z + q0[7] * kb.w;
        float s1 = q1[0] * ka.x + q1[1] * ka.y + q1[2] * ka.z + q1[3] * ka.w
                 + q1[4] * kb.x + q1[5] * kb.y + q1[6] * kb.z + q1[7] * kb.w;
        float p0 = exp2f(s0);
        float p1 = exp2f(s1);
        const float4 va = *(const float4*)&vs[m][0];
        const float4 vb = *(const float4*)&vs[m][4];
        d0 += p0; d1 += p1;
        acc0[0] += p0 * va.x; acc0[1] += p0 * va.y; acc0[2] += p0 * va.z; acc0[3] += p0 * va.w;
        acc0[4] += p0 * vb.x; acc0[5] += p0 * vb.y; acc0[6] += p0 * vb.z; acc0[7] += p0 * vb.w;
        acc1[0] += p1 * va.x; acc1[1] += p1 * va.y; acc1[2] += p1 * va.z; acc1[3] += p1 * va.w;
        acc1[4] += p1 * vb.x; acc1[5] += p1 * vb.y; acc1[6] += p1 * vb.z; acc1[7] += p1 * vb.w;
    }

    const float i0 = 1.f / d0, i1 = 1.f / d1;
    __syncthreads();   // qs fully consumed; reuse as output staging
    #pragma unroll
    for (int j = 0; j < 8; ++j) { qs[n0][j] = acc0[j] * i0; qs[n0 + 1][j] = acc1[j] * i1; }
    __syncthreads();

    #pragma unroll
    for (int j = 0; j < 4; ++j) {
        int idx  = tid + 256 * j;
        int n    = idx >> 1;
        int half = (idx & 1) * 4;
        *(float4*)(obuf + rowbase + (size_t)n * 64 + half) = *(const float4*)&qs[n][half];
    }
}

// ---------------------------------------------------------------------------
// Kernel 3: out = relu(O @ W10 + b10) @ W11 + b11
// grid RTOT/64, block 256. Two chained 64x64 GEMMs through LDS, thread 4x4.
// ---------------------------------------------------------------------------
__global__ __launch_bounds__(256) void proj_kernel(
    const float* __restrict__ obuf,
    const float* __restrict__ W10, const float* __restrict__ b10,
    const float* __restrict__ W11, const float* __restrict__ b11,
    float* __restrict__ out)
{
    __shared__ float Os[64][68];
    __shared__ float Ts[64][68];
    __shared__ float Was[64][68];
    __shared__ float Wbs[64][68];

    const int tid = threadIdx.x;
    const int tx  = tid & 15;     // cols tx*4..+3
    const int ty  = tid >> 4;     // rows ty*4..+3
    const size_t r0 = (size_t)blockIdx.x * 64;

    #pragma unroll
    for (int j = 0; j < 4; ++j) {
        int idx = tid + 256 * j;
        int r   = idx >> 4;
        int cq  = (idx & 15) * 4;
        *(float4*)&Os[r][cq]  = *(const float4*)(obuf + (r0 + (size_t)r) * 64 + cq);
        *(float4*)&Was[r][cq] = *(const float4*)(W10 + (size_t)r * 64 + cq);
        *(float4*)&Wbs[r][cq] = *(const float4*)(W11 + (size_t)r * 64 + cq);
    }
    __syncthreads();

    float acc[4][4];
    #pragma unroll
    for (int i = 0; i < 4; ++i)
        #pragma unroll
        for (int j = 0; j < 4; ++j) acc[i][j] = 0.f;

    #pragma unroll
    for (int k0 = 0; k0 < 64; k0 += 4) {
        float4 a[4], w[4];
        #pragma unroll
        for (int i = 0; i < 4; ++i) a[i] = *(const float4*)&Os[ty * 4 + i][k0];
        #pragma unroll
        for (int j = 0; j < 4; ++j) w[j] = *(const float4*)&Was[k0 + j][tx * 4];
        #pragma unroll
        for (int i = 0; i < 4; ++i) {
            acc[i][0] += a[i].x * w[0].x + a[i].y * w[1].x + a[i].z * w[2].x + a[i].w * w[3].x;
            acc[i][1] += a[i].x * w[0].y + a[i].y * w[1].y + a[i].z * w[2].y + a[i].w * w[3].y;
            acc[i][2] += a[i].x * w[0].z + a[i].y * w[1].z + a[i].z * w[2].z + a[i].w * w[3].z;
            acc[i][3] += a[i].x * w[0].w + a[i].y * w[1].w + a[i].z * w[2].w + a[i].w * w[3].w;
        }
    }

    const float4 ba = *(const float4*)(b10 + tx * 4);
    #pragma unroll
    for (int i = 0; i < 4; ++i) {
        float4 t;
        t.x = fmaxf(acc[i][0] + ba.x, 0.f);
        t.y = fmaxf(acc[i][1] + ba.y, 0.f);
        t.z = fmaxf(acc[i][2] + ba.z, 0.f);
        t.w = fmaxf(acc[i][3] + ba.w, 0.f);
        *(float4*)&Ts[ty * 4 + i][tx * 4] = t;
    }
    __syncthreads();

    #pragma unroll
    for (int i = 0; i < 4; ++i)
        #pragma unroll
        for (int j = 0; j < 4; ++j) acc[i][j] = 0.f;

    #pragma unroll
    for (int k0 = 0; k0 < 64; k0 += 4) {
        float4 a[4], w[4];
        #pragma unroll
        for (int i = 0; i < 4; ++i) a[i] = *(const float4*)&Ts[ty * 4 + i][k0];
        #pragma unroll
        for (int j = 0; j < 4; ++j) w[j] = *(const float4*)&Wbs[k0 + j][tx * 4];
        #pragma unroll
        for (int i = 0; i < 4; ++i) {
            acc[i][0] += a[i].x * w[0].x + a[i].y * w[1].x + a[i].z * w[2].x + a[i].w * w[3].x;
            acc[i][1] += a[i].x * w[0].y + a[i].y * w[1].y + a[i].z * w[2].y + a[i].w * w[3].y;
            acc[i][2] += a[i].x * w[0].z + a[i].y * w[1].z + a[i].z * w[2].z + a[i].w * w[3].z;
            acc[i][3] += a[i].x * w[0].w + a[i].y * w[1].w + a[i].z * w[2].w + a[i].w * w[3].w;
        }
    }

    const float4 bb = *(const float4*)(b11 + tx * 4);
    #pragma unroll
    for (int i = 0; i < 4; ++i) {
        float4 o;
        o.x = acc[i][0] + bb.x;
        o.y = acc[i][1] + bb.y;
        o.z = acc[i][2] + bb.z;
        o.w = acc[i][3] + bb.w;
        *(float4*)(out + (r0 + (size_t)(ty * 4 + i)) * 64 + tx * 4) = o;
    }
}

// ---------------------------------------------------------------------------
extern "C" void kernel_launch(void* const* d_in, const int* in_sizes, int n_in,
                              void* d_out, int out_size, void* d_ws, size_t ws_size,
                              hipStream_t stream)
{
    const float* X   = (const float*)d_in[0];
    const float* STE = (const float*)d_in[1];
    const float* W7  = (const float*)d_in[2];
    const float* b7  = (const float*)d_in[3];
    const float* W8  = (const float*)d_in[4];
    const float* b8  = (const float*)d_in[5];
    const float* W9  = (const float*)d_in[6];
    const float* b9  = (const float*)d_in[7];
    const float* W10 = (const float*)d_in[8];
    const float* b10 = (const float*)d_in[9];
    const float* W11 = (const float*)d_in[10];
    const float* b11 = (const float*)d_in[11];

    float* ws  = (float*)d_ws;   // Q | K | V | O  = 4 * 12.6 MB = 50.3 MB
    float* out = (float*)d_out;

    qkv_kernel<<<dim3(RTOT / 128, 3), 256, 0, stream>>>(X, STE, W7, b7, W8, b8, W9, b9, ws);
    attn_kernel<<<dim3(BT * 8), 256, 0, stream>>>(ws, ws + OOFF);
    proj_kernel<<<dim3(RTOT / 64), 256, 0, stream>>>(ws + OOFF, W10, b10, W11, b11, out);
}